// Round 8
// baseline (189.092 us; speedup 1.0000x reference)
//
#include <hip/hip_runtime.h>
#include <math.h>

#define ROI 7
#define NC 256          // channels per modality
#define TC 512          // 2*NC concatenated
#define HH 128
#define WW 128
#define HW (HH * WW)    // 16384

// ---------------------------------------------------------------------------
// Owner map: owner[b][y][x] = max anchor index n whose scattered 7x7 patch
// covers (y,x), else -1. Sequential overwrite == "last (max) anchor wins".
// ---------------------------------------------------------------------------
__global__ void init_owner_k(int* __restrict__ owner, int n) {
    int i = blockIdx.x * blockDim.x + threadIdx.x;
    if (i < n) owner[i] = -1;
}

__global__ void mark_owner_k(const float* __restrict__ anchors,
                             int* __restrict__ owner, int B, int N) {
    int i = blockIdx.x * blockDim.x + threadIdx.x;
    int total = B * N * 49;
    if (i >= total) return;
    int p = i % 49;
    int bn = i / 49;
    int n = bn % N;
    int b = bn / N;
    float ax = anchors[(size_t)(b * N + n) * 3 + 0];
    float ay = anchors[(size_t)(b * N + n) * 3 + 1];
    int x0 = (int)truncf(ax - 3.5f); x0 = min(max(x0, 0), WW - ROI);
    int y0 = (int)truncf(ay - 3.5f); y0 = min(max(y0, 0), HH - ROI);
    int x = x0 + (p % 7);
    int y = y0 + (p / 7);
    atomicMax(&owner[((size_t)b << 14) + (y << 7) + x], n);
}

// ---------------------------------------------------------------------------
struct BW { float w00, w01, w10, w11; };

__device__ inline BW bilin_weights(float X, float Y) {
    BW r;
    bool valid = (X >= -1.0f) && (X <= (float)WW) && (Y >= -1.0f) && (Y <= (float)HH);
    float x = fmaxf(X, 0.0f), y = fmaxf(Y, 0.0f);
    int ix = (int)floorf(x), iy = (int)floorf(y);
    int xl = min(ix, WW - 1);
    int yl = min(iy, HH - 1);
    float lx = (ix >= WW - 1) ? 0.0f : x - (float)xl;
    float ly = (iy >= HH - 1) ? 0.0f : y - (float)yl;
    float hx = 1.0f - lx, hy = 1.0f - ly;
    float s = valid ? 1.0f : 0.0f;
    r.w00 = hy * hx * s; r.w01 = hy * lx * s;
    r.w10 = ly * hx * s; r.w11 = ly * lx * s;
    return r;
}

// ---------------------------------------------------------------------------
// Merged kernel, 1 roi : 2 fuse interleave.
// fuse path: thread = (pixel-quad, 8-channel-pair group); float4 loads/stores
//   (1KB/wave-instr) -- 16 dwordx4 per thread instead of 64 dword.
// roi path: wave64 = 8x8 corner grid; 3 shfl_down recover the 4 corners.
// ---------------------------------------------------------------------------
__global__ __launch_bounds__(512) void fused_k(
        const float* __restrict__ rgb, const float* __restrict__ tir,
        const float* __restrict__ a_rgb, const float* __restrict__ a_tir,
        const float* __restrict__ wg, const float* __restrict__ bg,
        const float* __restrict__ wa, const float* __restrict__ ba,
        const int* __restrict__ owner, float* __restrict__ out,
        int N, int nRoi, int nFuse) {
    __shared__ float w[2 * TC];
    __shared__ float part0[64][33];
    __shared__ float part1[64][33];
    __shared__ __align__(16) float att[64];

    int bid = blockIdx.x;
    int tid = threadIdx.x;

    bool isRoi;
    int idx;
    if (nFuse == 2 * nRoi) {             // interleaved mapping (1 roi : 2 fuse)
        int q = bid / 3, r = bid - 3 * q;
        isRoi = (r == 0);
        idx = isRoi ? q : (bid - q - 1);
    } else {
        isRoi = (bid < nRoi);
        idx = isRoi ? bid : (bid - nRoi);
    }

    if (isRoi) {
        // ================= ROI align + fuse + owner-gated scatter =========
        int p  = tid & 63;
        int g  = tid >> 6;               // 0..7 -> 32 channels each
        int c0 = g << 5;
        int b = idx / N, n = idx % N;
        for (int i = tid; i < 2 * TC; i += 512) w[i] = wa[i];

        int lx = p & 7, ly = p >> 3;     // 8x8 corner-grid position
        bool isPt = (lx < 7) && (ly < 7);

        float axr = a_rgb[(size_t)(b * N + n) * 3 + 0];
        float ayr = a_rgb[(size_t)(b * N + n) * 3 + 1];
        float axt = a_tir[(size_t)(b * N + n) * 3 + 0];
        float ayt = a_tir[(size_t)(b * N + n) * 3 + 1];

        int gx0r = max(0, (int)floorf(axr - 3.0f));
        int gy0r = max(0, (int)floorf(ayr - 3.0f));
        int gx0t = max(0, (int)floorf(axt - 3.0f));
        int gy0t = max(0, (int)floorf(ayt - 3.0f));
        int offr = (min(gy0r + ly, HH - 1) << 7) + min(gx0r + lx, WW - 1);
        int offt = (min(gy0t + ly, HH - 1) << 7) + min(gx0t + lx, WW - 1);

        float Xr = (axr - 3.5f) + ((float)lx + 0.5f);
        float Yr = (ayr - 3.5f) + ((float)ly + 0.5f);
        float Xt = (axt - 3.5f) + ((float)lx + 0.5f);
        float Yt = (ayt - 3.5f) + ((float)ly + 0.5f);
        BW br = bilin_weights(Xr, Yr);
        BW bt = bilin_weights(Xt, Yt);

        int x0 = (int)truncf(axr - 3.5f); x0 = min(max(x0, 0), WW - ROI);
        int y0 = (int)truncf(ayr - 3.5f); y0 = min(max(y0, 0), HH - ROI);
        int x = x0 + lx, y = y0 + ly;
        bool act = isPt;
        if (act) act = (owner[((size_t)b << 14) + (y << 7) + x] == n);

        const float* rb = rgb + (((size_t)b * NC) << 14);
        const float* tb = tir + (((size_t)b * NC) << 14);

        __syncthreads();

        float vr[32], vt[32];
        float l0 = 0.f, l1 = 0.f;
        #pragma unroll
        for (int i = 0; i < 32; ++i) {
            int c = c0 + i;
            float gr0 = rb[((size_t)c << 14) + offr];
            float gt0 = tb[((size_t)c << 14) + offt];
            float gr1 = __shfl_down(gr0, 1, 64);
            float gr8 = __shfl_down(gr0, 8, 64);
            float gr9 = __shfl_down(gr0, 9, 64);
            float gt1 = __shfl_down(gt0, 1, 64);
            float gt8 = __shfl_down(gt0, 8, 64);
            float gt9 = __shfl_down(gt0, 9, 64);
            vr[i] = br.w00 * gr0 + br.w01 * gr1 + br.w10 * gr8 + br.w11 * gr9;
            vt[i] = bt.w00 * gt0 + bt.w01 * gt1 + bt.w10 * gt8 + bt.w11 * gt9;
            l0 = fmaf(w[c],          vr[i], fmaf(w[NC + c],     vt[i], l0));
            l1 = fmaf(w[2 * NC + c], vr[i], fmaf(w[3 * NC + c], vt[i], l1));
        }
        part0[p][g] = l0;
        part1[p][g] = l1;
        __syncthreads();
        if (g == 0 && isPt) {
            float L0 = ba[0], L1 = ba[1];
            #pragma unroll
            for (int s = 0; s < 8; ++s) { L0 += part0[p][s]; L1 += part1[p][s]; }
            float m = fmaxf(L0, L1);
            float e0 = expf(L0 - m), e1 = expf(L1 - m);
            att[p] = e0 / (e0 + e1);
        }
        __syncthreads();
        if (!act) return;

        float a0 = att[p];
        float* po = out + (((size_t)b * NC) << 14) + (y << 7) + x;
        #pragma unroll
        for (int i = 0; i < 32; ++i) {
            int c = c0 + i;
            po[(size_t)c << 14] = fmaf(a0, vr[i] - vt[i], vt[i]);
        }
    } else {
        // ================= global per-pixel fusion (float4) ===============
        int q  = tid & 15;               // pixel quad (4 px)
        int g  = tid >> 4;               // 0..31 -> 8 channel-pairs each
        int c0 = g << 3;
        int b = idx >> 8;                // 256 fuse-blocks per image
        int pix0 = (idx & 255) << 6;
        int px0 = q << 2;

        for (int i = tid; i < 2 * TC; i += 512) w[i] = wg[i];

        int4 ow4 = *reinterpret_cast<const int4*>(
            owner + (((size_t)b << 14) + pix0 + px0));
        bool av0 = ow4.x < 0, av1 = ow4.y < 0, av2 = ow4.z < 0, av3 = ow4.w < 0;
        bool any = av0 | av1 | av2 | av3;

        const float* pr = rgb + (((size_t)b * NC) << 14) + pix0 + px0;
        const float* pt = tir + (((size_t)b * NC) << 14) + pix0 + px0;

        __syncthreads();

        float4 vr4[8], vt4[8];
        float l0a = 0.f, l0b = 0.f, l0c = 0.f, l0d = 0.f;
        float l1a = 0.f, l1b = 0.f, l1c = 0.f, l1d = 0.f;
        if (any) {
            #pragma unroll
            for (int j = 0; j < 8; ++j) {
                int c = c0 + j;
                vr4[j] = *reinterpret_cast<const float4*>(pr + ((size_t)c << 14));
                vt4[j] = *reinterpret_cast<const float4*>(pt + ((size_t)c << 14));
                float wr0 = w[c], wt0 = w[NC + c];
                float wr1 = w[2 * NC + c], wt1 = w[3 * NC + c];
                l0a = fmaf(wr0, vr4[j].x, fmaf(wt0, vt4[j].x, l0a));
                l0b = fmaf(wr0, vr4[j].y, fmaf(wt0, vt4[j].y, l0b));
                l0c = fmaf(wr0, vr4[j].z, fmaf(wt0, vt4[j].z, l0c));
                l0d = fmaf(wr0, vr4[j].w, fmaf(wt0, vt4[j].w, l0d));
                l1a = fmaf(wr1, vr4[j].x, fmaf(wt1, vt4[j].x, l1a));
                l1b = fmaf(wr1, vr4[j].y, fmaf(wt1, vt4[j].y, l1b));
                l1c = fmaf(wr1, vr4[j].z, fmaf(wt1, vt4[j].z, l1c));
                l1d = fmaf(wr1, vr4[j].w, fmaf(wt1, vt4[j].w, l1d));
            }
            part0[px0 + 0][g] = l0a; part1[px0 + 0][g] = l1a;
            part0[px0 + 1][g] = l0b; part1[px0 + 1][g] = l1b;
            part0[px0 + 2][g] = l0c; part1[px0 + 2][g] = l1c;
            part0[px0 + 3][g] = l0d; part1[px0 + 3][g] = l1d;
        }
        __syncthreads();
        if (tid < 64) {
            float L0 = bg[0], L1 = bg[1];
            #pragma unroll
            for (int s = 0; s < 32; ++s) { L0 += part0[tid][s]; L1 += part1[tid][s]; }
            float m = fmaxf(L0, L1);
            float e0 = expf(L0 - m), e1 = expf(L1 - m);
            att[tid] = e0 / (e0 + e1);
        }
        __syncthreads();
        if (!any) return;

        float4 a4 = *reinterpret_cast<float4*>(&att[px0]);
        bool all4 = av0 & av1 & av2 & av3;
        float* po = out + (((size_t)b * NC) << 14) + pix0 + px0;
        #pragma unroll
        for (int j = 0; j < 8; ++j) {
            int c = c0 + j;
            float4 o;
            o.x = fmaf(a4.x, vr4[j].x - vt4[j].x, vt4[j].x);
            o.y = fmaf(a4.y, vr4[j].y - vt4[j].y, vt4[j].y);
            o.z = fmaf(a4.z, vr4[j].z - vt4[j].z, vt4[j].z);
            o.w = fmaf(a4.w, vr4[j].w - vt4[j].w, vt4[j].w);
            float* dst = po + ((size_t)c << 14);
            if (all4) {
                *reinterpret_cast<float4*>(dst) = o;
            } else {
                if (av0) dst[0] = o.x;
                if (av1) dst[1] = o.y;
                if (av2) dst[2] = o.z;
                if (av3) dst[3] = o.w;
            }
        }
    }
}

// ---------------------------------------------------------------------------
extern "C" void kernel_launch(void* const* d_in, const int* in_sizes, int n_in,
                              void* d_out, int out_size, void* d_ws, size_t ws_size,
                              hipStream_t stream) {
    const float* frgb = (const float*)d_in[0];
    const float* ftir = (const float*)d_in[1];
    const float* argb = (const float*)d_in[2];
    const float* atir = (const float*)d_in[3];
    const float* wg   = (const float*)d_in[4];
    const float* bgp  = (const float*)d_in[5];
    const float* wa   = (const float*)d_in[6];
    const float* bap  = (const float*)d_in[7];
    float* out = (float*)d_out;

    int B = in_sizes[0] / (NC * HW);       // 8
    int N = in_sizes[2] / (B * 3);         // 128
    int npix = B * HW;                     // 131072
    int nRoi = B * N;                      // 1024
    int nFuse = npix / 64;                 // 2048

    int* owner = (int*)d_ws;               // B*H*W ints = 512 KB

    init_owner_k<<<(npix + 255) / 256, 256, 0, stream>>>(owner, npix);
    mark_owner_k<<<(B * N * 49 + 255) / 256, 256, 0, stream>>>(argb, owner, B, N);
    fused_k<<<nRoi + nFuse, 512, 0, stream>>>(frgb, ftir, argb, atir,
                                              wg, bgp, wa, bap,
                                              owner, out, N, nRoi, nFuse);
}

// Round 9
// 188.832 us; speedup vs baseline: 1.0014x; 1.0014x over previous
//
#include <hip/hip_runtime.h>
#include <math.h>

#define ROI 7
#define NC 256          // channels per modality
#define TC 512          // 2*NC concatenated
#define HH 128
#define WW 128
#define HW (HH * WW)    // 16384

// ---------------------------------------------------------------------------
// Owner map: owner[b][y][x] = max anchor index n whose scattered 7x7 patch
// covers (y,x), else -1. Sequential overwrite == "last (max) anchor wins".
// ---------------------------------------------------------------------------
__global__ void init_owner_k(int* __restrict__ owner, int n) {
    int i = blockIdx.x * blockDim.x + threadIdx.x;
    if (i < n) owner[i] = -1;
}

__global__ void mark_owner_k(const float* __restrict__ anchors,
                             int* __restrict__ owner, int B, int N) {
    int i = blockIdx.x * blockDim.x + threadIdx.x;
    int total = B * N * 49;
    if (i >= total) return;
    int p = i % 49;
    int bn = i / 49;
    int n = bn % N;
    int b = bn / N;
    float ax = anchors[(size_t)(b * N + n) * 3 + 0];
    float ay = anchors[(size_t)(b * N + n) * 3 + 1];
    int x0 = (int)truncf(ax - 3.5f); x0 = min(max(x0, 0), WW - ROI);
    int y0 = (int)truncf(ay - 3.5f); y0 = min(max(y0, 0), HH - ROI);
    int x = x0 + (p % 7);
    int y = y0 + (p / 7);
    atomicMax(&owner[((size_t)b << 14) + (y << 7) + x], n);
}

// ---------------------------------------------------------------------------
struct BW { float w00, w01, w10, w11; };

__device__ inline BW bilin_weights(float X, float Y) {
    BW r;
    bool valid = (X >= -1.0f) && (X <= (float)WW) && (Y >= -1.0f) && (Y <= (float)HH);
    float x = fmaxf(X, 0.0f), y = fmaxf(Y, 0.0f);
    int ix = (int)floorf(x), iy = (int)floorf(y);
    int xl = min(ix, WW - 1);
    int yl = min(iy, HH - 1);
    float lx = (ix >= WW - 1) ? 0.0f : x - (float)xl;
    float ly = (iy >= HH - 1) ? 0.0f : y - (float)yl;
    float hx = 1.0f - lx, hy = 1.0f - ly;
    float s = valid ? 1.0f : 0.0f;
    r.w00 = hy * hx * s; r.w01 = hy * lx * s;
    r.w10 = ly * hx * s; r.w11 = ly * lx * s;
    return r;
}

// ---------------------------------------------------------------------------
// Merged kernel, 1 roi : 2 fuse interleave.
// __launch_bounds__(512, 4): VGPR cap 128, so the 64 per-thread value regs
// (held across the softmax barrier) stay in registers -- no scratch spill.
// fuse path: thread = (pixel-quad, 8-channel-pair group); float4 loads/stores.
// roi path: wave64 = 8x8 corner grid; 3 shfl_down recover the 4 corners.
// ---------------------------------------------------------------------------
__global__ __launch_bounds__(512, 4) void fused_k(
        const float* __restrict__ rgb, const float* __restrict__ tir,
        const float* __restrict__ a_rgb, const float* __restrict__ a_tir,
        const float* __restrict__ wg, const float* __restrict__ bg,
        const float* __restrict__ wa, const float* __restrict__ ba,
        const int* __restrict__ owner, float* __restrict__ out,
        int N, int nRoi, int nFuse) {
    __shared__ float w[2 * TC];
    __shared__ float part0[64][33];
    __shared__ float part1[64][33];
    __shared__ __align__(16) float att[64];

    int bid = blockIdx.x;
    int tid = threadIdx.x;

    bool isRoi;
    int idx;
    if (nFuse == 2 * nRoi) {             // interleaved mapping (1 roi : 2 fuse)
        int q = bid / 3, r = bid - 3 * q;
        isRoi = (r == 0);
        idx = isRoi ? q : (bid - q - 1);
    } else {
        isRoi = (bid < nRoi);
        idx = isRoi ? bid : (bid - nRoi);
    }

    if (isRoi) {
        // ================= ROI align + fuse + owner-gated scatter =========
        int p  = tid & 63;
        int g  = tid >> 6;               // 0..7 -> 32 channels each
        int c0 = g << 5;
        int b = idx / N, n = idx % N;
        for (int i = tid; i < 2 * TC; i += 512) w[i] = wa[i];

        int lx = p & 7, ly = p >> 3;     // 8x8 corner-grid position
        bool isPt = (lx < 7) && (ly < 7);

        float axr = a_rgb[(size_t)(b * N + n) * 3 + 0];
        float ayr = a_rgb[(size_t)(b * N + n) * 3 + 1];
        float axt = a_tir[(size_t)(b * N + n) * 3 + 0];
        float ayt = a_tir[(size_t)(b * N + n) * 3 + 1];

        int gx0r = max(0, (int)floorf(axr - 3.0f));
        int gy0r = max(0, (int)floorf(ayr - 3.0f));
        int gx0t = max(0, (int)floorf(axt - 3.0f));
        int gy0t = max(0, (int)floorf(ayt - 3.0f));
        int offr = (min(gy0r + ly, HH - 1) << 7) + min(gx0r + lx, WW - 1);
        int offt = (min(gy0t + ly, HH - 1) << 7) + min(gx0t + lx, WW - 1);

        float Xr = (axr - 3.5f) + ((float)lx + 0.5f);
        float Yr = (ayr - 3.5f) + ((float)ly + 0.5f);
        float Xt = (axt - 3.5f) + ((float)lx + 0.5f);
        float Yt = (ayt - 3.5f) + ((float)ly + 0.5f);
        BW br = bilin_weights(Xr, Yr);
        BW bt = bilin_weights(Xt, Yt);

        int x0 = (int)truncf(axr - 3.5f); x0 = min(max(x0, 0), WW - ROI);
        int y0 = (int)truncf(ayr - 3.5f); y0 = min(max(y0, 0), HH - ROI);
        int x = x0 + lx, y = y0 + ly;
        bool act = isPt;
        if (act) act = (owner[((size_t)b << 14) + (y << 7) + x] == n);

        const float* rb = rgb + (((size_t)b * NC) << 14);
        const float* tb = tir + (((size_t)b * NC) << 14);

        __syncthreads();

        float vr[32], vt[32];
        float l0 = 0.f, l1 = 0.f;
        #pragma unroll
        for (int i = 0; i < 32; ++i) {
            int c = c0 + i;
            float gr0 = rb[((size_t)c << 14) + offr];
            float gt0 = tb[((size_t)c << 14) + offt];
            float gr1 = __shfl_down(gr0, 1, 64);
            float gr8 = __shfl_down(gr0, 8, 64);
            float gr9 = __shfl_down(gr0, 9, 64);
            float gt1 = __shfl_down(gt0, 1, 64);
            float gt8 = __shfl_down(gt0, 8, 64);
            float gt9 = __shfl_down(gt0, 9, 64);
            vr[i] = br.w00 * gr0 + br.w01 * gr1 + br.w10 * gr8 + br.w11 * gr9;
            vt[i] = bt.w00 * gt0 + bt.w01 * gt1 + bt.w10 * gt8 + bt.w11 * gt9;
            l0 = fmaf(w[c],          vr[i], fmaf(w[NC + c],     vt[i], l0));
            l1 = fmaf(w[2 * NC + c], vr[i], fmaf(w[3 * NC + c], vt[i], l1));
        }
        part0[p][g] = l0;
        part1[p][g] = l1;
        __syncthreads();
        if (g == 0 && isPt) {
            float L0 = ba[0], L1 = ba[1];
            #pragma unroll
            for (int s = 0; s < 8; ++s) { L0 += part0[p][s]; L1 += part1[p][s]; }
            float m = fmaxf(L0, L1);
            float e0 = expf(L0 - m), e1 = expf(L1 - m);
            att[p] = e0 / (e0 + e1);
        }
        __syncthreads();
        if (!act) return;

        float a0 = att[p];
        float* po = out + (((size_t)b * NC) << 14) + (y << 7) + x;
        #pragma unroll
        for (int i = 0; i < 32; ++i) {
            int c = c0 + i;
            po[(size_t)c << 14] = fmaf(a0, vr[i] - vt[i], vt[i]);
        }
    } else {
        // ================= global per-pixel fusion (float4) ===============
        int q  = tid & 15;               // pixel quad (4 px)
        int g  = tid >> 4;               // 0..31 -> 8 channel-pairs each
        int c0 = g << 3;
        int b = idx >> 8;                // 256 fuse-blocks per image
        int pix0 = (idx & 255) << 6;
        int px0 = q << 2;

        for (int i = tid; i < 2 * TC; i += 512) w[i] = wg[i];

        int4 ow4 = *reinterpret_cast<const int4*>(
            owner + (((size_t)b << 14) + pix0 + px0));
        bool av0 = ow4.x < 0, av1 = ow4.y < 0, av2 = ow4.z < 0, av3 = ow4.w < 0;
        bool any = av0 | av1 | av2 | av3;

        const float* pr = rgb + (((size_t)b * NC) << 14) + pix0 + px0;
        const float* pt = tir + (((size_t)b * NC) << 14) + pix0 + px0;

        __syncthreads();

        float4 vr4[8], vt4[8];
        float l0a = 0.f, l0b = 0.f, l0c = 0.f, l0d = 0.f;
        float l1a = 0.f, l1b = 0.f, l1c = 0.f, l1d = 0.f;
        if (any) {
            #pragma unroll
            for (int j = 0; j < 8; ++j) {
                int c = c0 + j;
                vr4[j] = *reinterpret_cast<const float4*>(pr + ((size_t)c << 14));
                vt4[j] = *reinterpret_cast<const float4*>(pt + ((size_t)c << 14));
                float wr0 = w[c], wt0 = w[NC + c];
                float wr1 = w[2 * NC + c], wt1 = w[3 * NC + c];
                l0a = fmaf(wr0, vr4[j].x, fmaf(wt0, vt4[j].x, l0a));
                l0b = fmaf(wr0, vr4[j].y, fmaf(wt0, vt4[j].y, l0b));
                l0c = fmaf(wr0, vr4[j].z, fmaf(wt0, vt4[j].z, l0c));
                l0d = fmaf(wr0, vr4[j].w, fmaf(wt0, vt4[j].w, l0d));
                l1a = fmaf(wr1, vr4[j].x, fmaf(wt1, vt4[j].x, l1a));
                l1b = fmaf(wr1, vr4[j].y, fmaf(wt1, vt4[j].y, l1b));
                l1c = fmaf(wr1, vr4[j].z, fmaf(wt1, vt4[j].z, l1c));
                l1d = fmaf(wr1, vr4[j].w, fmaf(wt1, vt4[j].w, l1d));
            }
            part0[px0 + 0][g] = l0a; part1[px0 + 0][g] = l1a;
            part0[px0 + 1][g] = l0b; part1[px0 + 1][g] = l1b;
            part0[px0 + 2][g] = l0c; part1[px0 + 2][g] = l1c;
            part0[px0 + 3][g] = l0d; part1[px0 + 3][g] = l1d;
        }
        __syncthreads();
        if (tid < 64) {
            float L0 = bg[0], L1 = bg[1];
            #pragma unroll
            for (int s = 0; s < 32; ++s) { L0 += part0[tid][s]; L1 += part1[tid][s]; }
            float m = fmaxf(L0, L1);
            float e0 = expf(L0 - m), e1 = expf(L1 - m);
            att[tid] = e0 / (e0 + e1);
        }
        __syncthreads();
        if (!any) return;

        float4 a4 = *reinterpret_cast<float4*>(&att[px0]);
        bool all4 = av0 & av1 & av2 & av3;
        float* po = out + (((size_t)b * NC) << 14) + pix0 + px0;
        #pragma unroll
        for (int j = 0; j < 8; ++j) {
            int c = c0 + j;
            float4 o;
            o.x = fmaf(a4.x, vr4[j].x - vt4[j].x, vt4[j].x);
            o.y = fmaf(a4.y, vr4[j].y - vt4[j].y, vt4[j].y);
            o.z = fmaf(a4.z, vr4[j].z - vt4[j].z, vt4[j].z);
            o.w = fmaf(a4.w, vr4[j].w - vt4[j].w, vt4[j].w);
            float* dst = po + ((size_t)c << 14);
            if (all4) {
                *reinterpret_cast<float4*>(dst) = o;
            } else {
                if (av0) dst[0] = o.x;
                if (av1) dst[1] = o.y;
                if (av2) dst[2] = o.z;
                if (av3) dst[3] = o.w;
            }
        }
    }
}

// ---------------------------------------------------------------------------
extern "C" void kernel_launch(void* const* d_in, const int* in_sizes, int n_in,
                              void* d_out, int out_size, void* d_ws, size_t ws_size,
                              hipStream_t stream) {
    const float* frgb = (const float*)d_in[0];
    const float* ftir = (const float*)d_in[1];
    const float* argb = (const float*)d_in[2];
    const float* atir = (const float*)d_in[3];
    const float* wg   = (const float*)d_in[4];
    const float* bgp  = (const float*)d_in[5];
    const float* wa   = (const float*)d_in[6];
    const float* bap  = (const float*)d_in[7];
    float* out = (float*)d_out;

    int B = in_sizes[0] / (NC * HW);       // 8
    int N = in_sizes[2] / (B * 3);         // 128
    int npix = B * HW;                     // 131072
    int nRoi = B * N;                      // 1024
    int nFuse = npix / 64;                 // 2048

    int* owner = (int*)d_ws;               // B*H*W ints = 512 KB

    init_owner_k<<<(npix + 255) / 256, 256, 0, stream>>>(owner, npix);
    mark_owner_k<<<(B * N * 49 + 255) / 256, 256, 0, stream>>>(argb, owner, B, N);
    fused_k<<<nRoi + nFuse, 512, 0, stream>>>(frgb, ftir, argb, atir,
                                              wg, bgp, wa, bap,
                                              owner, out, N, nRoi, nFuse);
}